// Round 16
// baseline (302.134 us; speedup 1.0000x reference)
//
#include <hip/hip_runtime.h>

#define NN 100000
#define NE 600000
#define CC 128
#define CVB2 3125            // NN*CC / 4096 (conversion blocks per array)
#define AB 6250              // NN / 16 (nodes per agg block = 16)
#define GBD 782              // ceil(NN / 128)
#define NBK 49               // coarse buckets per graph (dst >> 11)
#define BCAP 16384           // csr slots per bucket (expected ~12245, 34 sigma)
#define EPB 8192             // edges per block in bucket pass
#define BBLK 74              // ceil(NE / EPB)
#define CCAP 320             // chunk slots per (block,bucket): mean 167, 12 sigma

typedef __attribute__((ext_vector_type(8))) short short8v;
typedef __attribute__((ext_vector_type(8))) unsigned short ushort8v;
typedef __attribute__((ext_vector_type(4))) unsigned short ushort4v;
typedef __attribute__((ext_vector_type(4))) float float4v;

__device__ __forceinline__ unsigned short f2bf(float f) {
    union { float f; unsigned u; } c; c.f = f;
    unsigned r = c.u + 0x7FFFu + ((c.u >> 16) & 1u);   // RNE
    return (unsigned short)(r >> 16);
}
__device__ __forceinline__ float bf2f(unsigned short u) {
    union { unsigned u; float f; } c; c.u = (unsigned)u << 16;
    return c.f;
}
__device__ __forceinline__ void addu8(float4& lo, float4& hi, ushort8v u) {
    lo.x += bf2f(u[0]); lo.y += bf2f(u[1]); lo.z += bf2f(u[2]); lo.w += bf2f(u[3]);
    hi.x += bf2f(u[4]); hi.y += bf2f(u[5]); hi.z += bf2f(u[6]); hi.w += bf2f(u[7]);
}
__device__ __forceinline__ ushort8v cvt8(const float* p) {
    float4 a = *reinterpret_cast<const float4*>(p);
    float4 b = *reinterpret_cast<const float4*>(p + 4);
    ushort8v h;
    h[0] = f2bf(a.x); h[1] = f2bf(a.y); h[2] = f2bf(a.z); h[3] = f2bf(a.w);
    h[4] = f2bf(b.x); h[5] = f2bf(b.y); h[6] = f2bf(b.z); h[7] = f2bf(b.w);
    return h;
}

// ---- k_preall: edge bucketing (private per-block chunks, NO global atomics)
// + x->bf16 + W->bf16, one launch. cnts[] written unconditionally -> no
// persistent state, no memset needed.

__global__ __launch_bounds__(256)
void k_preall(const int* __restrict__ ei0, const int* __restrict__ ei1,
              int* __restrict__ cnts, int2* __restrict__ bkt,
              const float* __restrict__ xu, const float* __restrict__ xi,
              unsigned short* __restrict__ xbu, unsigned short* __restrict__ xbi,
              const float* w0, const float* w1, const float* w2, const float* w3,
              const float* w4, const float* w5, const float* w6, const float* w7,
              unsigned short* __restrict__ Wb) {
    __shared__ int hist[NBK];
    int bid = blockIdx.x, t = threadIdx.x;
    if (bid < 2 * BBLK) {
        int g = (bid >= BBLK) ? 1 : 0;
        const int* ei = g ? ei1 : ei0;
        int local = g ? bid - BBLK : bid;
        int e0 = local * EPB;
        int cnt = NE - e0; if (cnt > EPB) cnt = EPB;
        if (t < NBK) hist[t] = 0;
        __syncthreads();
        for (int i = t; i < cnt; i += 256)
            atomicAdd(&hist[ei[NE + e0 + i] >> 11], 1);
        __syncthreads();
        if (t < NBK) {
            cnts[(g * NBK + t) * BBLK + local] = hist[t];
            hist[t] = 0;                    // reuse as local cursor
        }
        __syncthreads();
        for (int i = t; i < cnt; i += 256) {
            int dst = ei[NE + e0 + i];
            int src = ei[e0 + i];
            int b = dst >> 11;
            int r = atomicAdd(&hist[b], 1);
            if (r < CCAP)
                bkt[(((size_t)g * NBK + b) * BBLK + local) * CCAP + r] =
                    make_int2(src, dst);
        }
        return;
    }
    bid -= 2 * BBLK;
    if (bid < 2 * CVB2) {
        const float* src = (bid < CVB2) ? xu : xi;
        unsigned short* dst = (bid < CVB2) ? xbu : xbi;
        int local = (bid < CVB2) ? bid : bid - CVB2;
        size_t idx = (size_t)local * 4096 + t * 8;
        ushort8v a = cvt8(src + idx);
        ushort8v b = cvt8(src + idx + 2048);
        *reinterpret_cast<ushort8v*>(dst + idx) = a;
        *reinterpret_cast<ushort8v*>(dst + idx + 2048) = b;
        return;
    }
    bid -= 2 * CVB2;
    int m = bid >> 3;
    const float* src = w0;
    if (m == 1) src = w1; else if (m == 2) src = w2; else if (m == 3) src = w3;
    else if (m == 4) src = w4; else if (m == 5) src = w5;
    else if (m == 6) src = w6; else if (m == 7) src = w7;
    size_t idx = (size_t)(bid & 7) * 2048 + t * 8;
    *reinterpret_cast<ushort8v*>(Wb + (size_t)m * 16384 + idx) = cvt8(src + idx);
}

// ---- k_csr: per-bucket counting sort over private chunks -> CSR + rp/re ----
// Slot-scan over BBLK*CCAP slots (predicated on chunk count); deg-count /
// prefix-scan / scatter machinery verbatim from the verified kernel.

__global__ __launch_bounds__(256)
void k_csr(const int* __restrict__ cnts, const int2* __restrict__ bkt,
           int* __restrict__ rp0, int* __restrict__ re0,
           int* __restrict__ rp1, int* __restrict__ re1,
           int* __restrict__ csr) {
    __shared__ int deg[2048];
    __shared__ int curp[2048];
    __shared__ int s[256];
    __shared__ int scnt[BBLK];
    int bid = blockIdx.x;
    int g = (bid >= NBK) ? 1 : 0;
    int bb = g ? bid - NBK : bid;
    int t = threadIdx.x;
    const int2* bbase = bkt + ((size_t)g * NBK + bb) * BBLK * CCAP;
    int dbase = bb * 2048;
    int cb = (g * NBK + bb) * BCAP;
    int* rp = g ? rp1 : rp0;
    int* re = g ? re1 : re0;
    if (t < BBLK) {
        int c = cnts[(g * NBK + bb) * BBLK + t];
        scnt[t] = (c < CCAP) ? c : CCAP;
    }
    for (int i = t; i < 2048; i += 256) deg[i] = 0;
    __syncthreads();
    for (int sidx = t; sidx < BBLK * CCAP; sidx += 256) {
        int blk = sidx / CCAP;
        int idx = sidx - blk * CCAP;
        if (idx < scnt[blk]) {
            int2 e = bbase[sidx];
            atomicAdd(&deg[e.y - dbase], 1);
        }
    }
    __syncthreads();
    int loc[8]; int v = 0; int b8 = t * 8;
#pragma unroll
    for (int u = 0; u < 8; ++u) { loc[u] = deg[b8 + u]; v += loc[u]; }
    s[t] = v; __syncthreads();
    for (int off = 1; off < 256; off <<= 1) {
        int x = (t >= off) ? s[t - off] : 0;
        __syncthreads();
        s[t] += x;
        __syncthreads();
    }
    int run = s[t] - v;
#pragma unroll
    for (int u = 0; u < 8; ++u) {
        int d = b8 + u;
        int gd = dbase + d;
        int start = cb + run;
        curp[d] = start;
        if (gd < NN) { rp[gd] = start; re[gd] = start + loc[u]; }
        run += loc[u];
    }
    __syncthreads();
    for (int sidx = t; sidx < BBLK * CCAP; sidx += 256) {
        int blk = sidx / CCAP;
        int idx = sidx - blk * CCAP;
        if (idx < scnt[blk]) {
            int2 e = bbase[sidx];
            int p = atomicAdd(&curp[e.y - dbase], 1);
            if (p < cb + BCAP) csr[p] = e.x;
        }
    }
}

// ------------- aggregation (both directions in one launch), bf16 -------------

__global__ __launch_bounds__(256)
void k_agg2(const unsigned short* __restrict__ s0, const int* __restrict__ rp0,
            const int* __restrict__ re0, unsigned short* __restrict__ m0,
            const unsigned short* __restrict__ s1, const int* __restrict__ rp1,
            const int* __restrict__ re1, unsigned short* __restrict__ m1,
            const int* __restrict__ csr) {
    int bid = blockIdx.x;
    const unsigned short* src; const int* rp; const int* re; unsigned short* mean;
    if (bid < AB) { src = s0; rp = rp0; re = re0; mean = m0; }
    else { bid -= AB; src = s1; rp = rp1; re = re1; mean = m1; }
    int t = threadIdx.x;
    int node = bid * 16 + (t >> 4);
    int j0 = (t & 15) * 8;
    int b = rp[node], e = re[node];
    float4 z = make_float4(0.f, 0.f, 0.f, 0.f);
    float4 l0 = z, h0 = z, l1 = z, h1 = z, l2 = z, h2 = z, l3 = z, h3 = z;
    int i = b;
    for (; i + 4 <= e; i += 4) {
        int a = csr[i], bb = csr[i + 1], c = csr[i + 2], d = csr[i + 3];
        ushort8v u0 = *reinterpret_cast<const ushort8v*>(src + (size_t)a * CC + j0);
        ushort8v u1 = *reinterpret_cast<const ushort8v*>(src + (size_t)bb * CC + j0);
        ushort8v u2 = *reinterpret_cast<const ushort8v*>(src + (size_t)c * CC + j0);
        ushort8v u3 = *reinterpret_cast<const ushort8v*>(src + (size_t)d * CC + j0);
        addu8(l0, h0, u0); addu8(l1, h1, u1); addu8(l2, h2, u2); addu8(l3, h3, u3);
    }
    for (; i + 2 <= e; i += 2) {
        int a = csr[i], bb = csr[i + 1];
        ushort8v u0 = *reinterpret_cast<const ushort8v*>(src + (size_t)a * CC + j0);
        ushort8v u1 = *reinterpret_cast<const ushort8v*>(src + (size_t)bb * CC + j0);
        addu8(l0, h0, u0); addu8(l1, h1, u1);
    }
    if (i < e) {
        int a = csr[i];
        addu8(l0, h0, *reinterpret_cast<const ushort8v*>(src + (size_t)a * CC + j0));
    }
    int dg = e - b;
    float inv = 1.f / (float)(dg > 1 ? dg : 1);
    float m_[8];
    m_[0] = ((l0.x + l1.x) + (l2.x + l3.x)) * inv;
    m_[1] = ((l0.y + l1.y) + (l2.y + l3.y)) * inv;
    m_[2] = ((l0.z + l1.z) + (l2.z + l3.z)) * inv;
    m_[3] = ((l0.w + l1.w) + (l2.w + l3.w)) * inv;
    m_[4] = ((h0.x + h1.x) + (h2.x + h3.x)) * inv;
    m_[5] = ((h0.y + h1.y) + (h2.y + h3.y)) * inv;
    m_[6] = ((h0.z + h1.z) + (h2.z + h3.z)) * inv;
    m_[7] = ((h0.w + h1.w) + (h2.w + h3.w)) * inv;
    ushort8v h;
#pragma unroll
    for (int k = 0; k < 8; ++k) h[k] = f2bf(m_[k]);
    *reinterpret_cast<ushort8v*>(mean + (size_t)node * CC + j0) = h;
}

// ------- MFMA fused GEMM+LN+ReLU, both directions in one launch -------
// Round-12 verified structure: 1024 thr = 16 waves (2 mg x 8 ng), tile 128x128,
// K=256, all-bf16, hoisted Wl fragments, LN epilogue under t < 512.

template<bool OUTF32>
__global__ __launch_bounds__(1024, 4)
void k_gemm2(const unsigned short* __restrict__ mean0, const unsigned short* __restrict__ x0,
             const unsigned short* __restrict__ wl0, const unsigned short* __restrict__ wr0,
             const float* __restrict__ bl0, const float* __restrict__ g0,
             const float* __restrict__ bb0, void* __restrict__ out0,
             const unsigned short* __restrict__ mean1, const unsigned short* __restrict__ x1,
             const unsigned short* __restrict__ wl1, const unsigned short* __restrict__ wr1,
             const float* __restrict__ bl1, const float* __restrict__ g1,
             const float* __restrict__ bb1, void* __restrict__ out1) {
    __shared__ char sA[128 * 512];              // 64 KB bf16 A tile, then fp32 LN buf
    __shared__ float sbl[128], sg[128], sb[128];

    int bid = blockIdx.x;
    const unsigned short *mean, *xs, *wl, *wr;
    const float *bl, *g, *bb;
    void* out;
    if (bid < GBD) { mean = mean0; xs = x0; wl = wl0; wr = wr0; bl = bl0; g = g0; bb = bb0; out = out0; }
    else { bid -= GBD; mean = mean1; xs = x1; wl = wl1; wr = wr1; bl = bl1; g = g1; bb = bb1; out = out1; }

    int t = threadIdx.x;
    int base = bid * 128;
    if (t < 128) { sbl[t] = bl[t]; sg[t] = g[t]; sb[t] = bb[t]; }

    int wid = t >> 6, l = t & 63;
    int mg = wid >> 3, ng = wid & 7;        // 2 mg x 8 ng
    int l15 = l & 15, l4 = l >> 4;

    // ---- hoisted: khalf=0 (Wl) B-fragments, issued before staging ----
    short8v bf0[4];
    {
        int j = ng * 16 + l15;
        const unsigned short* wrow = wl + (size_t)j * CC + l4 * 8;
#pragma unroll
        for (int kk4 = 0; kk4 < 4; ++kk4)
            bf0[kk4] = *reinterpret_cast<const short8v*>(wrow + kk4 * 32);
    }

    // ---- stage A tile (both halves bf16): 8 threads/row ----
    {
        int r = t >> 3, q = t & 7;
        int swz = (r & 7) << 4;
        int node = base + r;
        bool valid = node < NN;
        const unsigned short* mrow = mean + (size_t)node * CC;
        const unsigned short* xrow = xs + (size_t)node * CC;
        ushort8v zz = (ushort8v){0, 0, 0, 0, 0, 0, 0, 0};
#pragma unroll
        for (int j = 0; j < 2; ++j) {
            int col = (j * 8 + q) * 8;
            ushort8v hm = valid ? *reinterpret_cast<const ushort8v*>(mrow + col) : zz;
            *reinterpret_cast<ushort8v*>(sA + ((r * 512 + col * 2) ^ swz)) = hm;
            ushort8v hx = valid ? *reinterpret_cast<const ushort8v*>(xrow + col) : zz;
            *reinterpret_cast<ushort8v*>(sA + ((r * 512 + 256 + col * 2) ^ swz)) = hx;
        }
    }
    __syncthreads();

    float4v acc[4];
#pragma unroll
    for (int mt = 0; mt < 4; ++mt)
        acc[mt] = (float4v){0.f, 0.f, 0.f, 0.f};

    // ---- khalf = 0 (mean half, Wl) ----
#pragma unroll
    for (int kk4 = 0; kk4 < 4; ++kk4) {
        short8v af[4];
#pragma unroll
        for (int mt = 0; mt < 4; ++mt) {
            int row = mg * 64 + mt * 16 + l15;
            int byte = (row * 512 + l4 * 16 + kk4 * 64) ^ ((row & 7) << 4);
            af[mt] = *reinterpret_cast<short8v*>(sA + byte);
        }
#pragma unroll
        for (int mt = 0; mt < 4; ++mt)
            acc[mt] = __builtin_amdgcn_mfma_f32_16x16x32_bf16(
                af[mt], bf0[kk4], acc[mt], 0, 0, 0);
    }

    // ---- khalf = 1 (x half, Wr) ----
    {
        short8v bf1[4];
        {
            int j = ng * 16 + l15;
            const unsigned short* wrow = wr + (size_t)j * CC + l4 * 8;
#pragma unroll
            for (int kk4 = 0; kk4 < 4; ++kk4)
                bf1[kk4] = *reinterpret_cast<const short8v*>(wrow + kk4 * 32);
        }
#pragma unroll
        for (int kk4 = 0; kk4 < 4; ++kk4) {
            short8v af[4];
#pragma unroll
            for (int mt = 0; mt < 4; ++mt) {
                int row = mg * 64 + mt * 16 + l15;
                int byte = (row * 512 + l4 * 16 + (4 + kk4) * 64) ^ ((row & 7) << 4);
                af[mt] = *reinterpret_cast<short8v*>(sA + byte);
            }
#pragma unroll
            for (int mt = 0; mt < 4; ++mt)
                acc[mt] = __builtin_amdgcn_mfma_f32_16x16x32_bf16(
                    af[mt], bf1[kk4], acc[mt], 0, 0, 0);
        }
    }
    __syncthreads();   // A tile free; reuse as fp32 LN buffer

    // ---- scatter biased acc -> LDS fp32 (same swizzle) ----
#pragma unroll
    for (int mt = 0; mt < 4; ++mt)
#pragma unroll
        for (int r4 = 0; r4 < 4; ++r4) {
            int nrow = mg * 64 + mt * 16 + l4 * 4 + r4;
            int col = ng * 16 + l15;
            float v = acc[mt][r4] + sbl[col];
            int byte = (nrow * 512 + col * 4) ^ ((nrow & 7) << 4);
            *reinterpret_cast<float*>(sA + byte) = v;
        }
    __syncthreads();

    // ---- transposed LN + ReLU + store (verbatim round-7 path, t < 512) ----
    if (t < 512) {
        int nn_ = t >> 2, qq = t & 3;
        int gnode = base + nn_;
        float s1 = 0.f, s2 = 0.f;
        float4 vv[8];
#pragma unroll
        for (int u = 0; u < 8; ++u) {
            int c = qq * 4 + u * 16;
            int byte = (nn_ * 512 + c * 4) ^ ((nn_ & 7) << 4);
            float4 vx = *reinterpret_cast<float4*>(sA + byte);
            vv[u] = vx;
            s1 += vx.x + vx.y + vx.z + vx.w;
            s2 += vx.x * vx.x + vx.y * vx.y + vx.z * vx.z + vx.w * vx.w;
        }
        s1 += __shfl_xor(s1, 1); s1 += __shfl_xor(s1, 2);
        s2 += __shfl_xor(s2, 1); s2 += __shfl_xor(s2, 2);
        float mu = s1 * (1.f / 128.f);
        float var = s2 * (1.f / 128.f) - mu * mu;
        float rstd = rsqrtf(var + 1e-5f);
        if (gnode < NN) {
#pragma unroll
            for (int u = 0; u < 8; ++u) {
                int c = qq * 4 + u * 16;
                float4 vx = vv[u];
                float4 o;
                o.x = fmaxf(0.f, (vx.x - mu) * rstd * sg[c + 0] + sb[c + 0]);
                o.y = fmaxf(0.f, (vx.y - mu) * rstd * sg[c + 1] + sb[c + 1]);
                o.z = fmaxf(0.f, (vx.z - mu) * rstd * sg[c + 2] + sb[c + 2]);
                o.w = fmaxf(0.f, (vx.w - mu) * rstd * sg[c + 3] + sb[c + 3]);
                if (OUTF32) {
                    float* op = (float*)out + (size_t)gnode * CC;
                    *reinterpret_cast<float4*>(op + c) = o;
                } else {
                    unsigned short* op = (unsigned short*)out + (size_t)gnode * CC;
                    ushort4v h; h.x = f2bf(o.x); h.y = f2bf(o.y); h.z = f2bf(o.z); h.w = f2bf(o.w);
                    *reinterpret_cast<ushort4v*>(op + c) = h;
                }
            }
        }
    }
}

// ---------------- launch ----------------

extern "C" void kernel_launch(void* const* d_in, const int* in_sizes, int n_in,
                              void* d_out, int out_size, void* d_ws, size_t ws_size,
                              hipStream_t stream) {
    const float* x_user = (const float*)d_in[0];
    const float* x_item = (const float*)d_in[1];
    const int* ei_ui = (const int*)d_in[2];
    const int* ei_iu = (const int*)d_in[3];

    const float* Wl_ui[2] = {(const float*)d_in[4],  (const float*)d_in[14]};
    const float* bl_ui[2] = {(const float*)d_in[5],  (const float*)d_in[15]};
    const float* Wr_ui[2] = {(const float*)d_in[6],  (const float*)d_in[16]};
    const float* Wl_iu[2] = {(const float*)d_in[7],  (const float*)d_in[17]};
    const float* bl_iu[2] = {(const float*)d_in[8],  (const float*)d_in[18]};
    const float* Wr_iu[2] = {(const float*)d_in[9],  (const float*)d_in[19]};
    const float* g_user[2] = {(const float*)d_in[10], (const float*)d_in[20]};
    const float* b_user[2] = {(const float*)d_in[11], (const float*)d_in[21]};
    const float* g_item[2] = {(const float*)d_in[12], (const float*)d_in[22]};
    const float* b_item[2] = {(const float*)d_in[13], (const float*)d_in[23]};

    auto align = [](size_t x) { return (x + 255) & ~(size_t)255; };
    char* w = (char*)d_ws;
    int* cnts = (int*)w; w += align((size_t)2 * NBK * BBLK * 4);
    int2* bkt = (int2*)w; w += align((size_t)2 * NBK * BBLK * CCAP * 8);
    int* csr = (int*)w; w += align((size_t)2 * NBK * BCAP * 4);
    int* rp_ui = (int*)w; w += align((size_t)NN * 4);
    int* re_ui = (int*)w; w += align((size_t)NN * 4);
    int* rp_iu = (int*)w; w += align((size_t)NN * 4);
    int* re_iu = (int*)w; w += align((size_t)NN * 4);
    unsigned short* Wb = (unsigned short*)w; w += align((size_t)8 * 16384 * 2);
    unsigned short* xb_user = (unsigned short*)w; w += align((size_t)NN * CC * 2);
    unsigned short* xb_item = (unsigned short*)w; w += align((size_t)NN * CC * 2);
    unsigned short* w_user = (unsigned short*)w; w += align((size_t)NN * CC * 2);
    unsigned short* w_item = (unsigned short*)w; w += align((size_t)NN * CC * 2);
    unsigned short* mean_item = (unsigned short*)w; w += align((size_t)NN * CC * 2);
    unsigned short* mean_user = (unsigned short*)w; w += align((size_t)NN * CC * 2);

    float* out_user = (float*)d_out;
    float* out_item = (float*)d_out + (size_t)NN * CC;

    // ---- bucketing (private chunks) + all bf16 conversions, one launch ----
    k_preall<<<2 * BBLK + 2 * CVB2 + 64, 256, 0, stream>>>(
        ei_ui, ei_iu, cnts, bkt,
        x_user, x_item, xb_user, xb_item,
        Wl_ui[0], Wr_ui[0], Wl_iu[0], Wr_iu[0],
        Wl_ui[1], Wr_ui[1], Wl_iu[1], Wr_iu[1], Wb);
    k_csr<<<2 * NBK, 256, 0, stream>>>(cnts, bkt, rp_ui, re_ui, rp_iu, re_iu, csr);

    // ---- layer 0 (all bf16) ----
    k_agg2<<<2 * AB, 256, 0, stream>>>(xb_user, rp_ui, re_ui, mean_item,
                                       xb_item, rp_iu, re_iu, mean_user, csr);
    k_gemm2<false><<<2 * GBD, 1024, 0, stream>>>(
        mean_item, xb_item, Wb + 0 * 16384, Wb + 1 * 16384,
        bl_ui[0], g_item[0], b_item[0], w_item,
        mean_user, xb_user, Wb + 2 * 16384, Wb + 3 * 16384,
        bl_iu[0], g_user[0], b_user[0], w_user);

    // ---- layer 1 (all bf16) ----
    k_agg2<<<2 * AB, 256, 0, stream>>>(w_user, rp_ui, re_ui, mean_item,
                                       w_item, rp_iu, re_iu, mean_user, csr);
    k_gemm2<true><<<2 * GBD, 1024, 0, stream>>>(
        mean_item, w_item, Wb + 4 * 16384, Wb + 5 * 16384,
        bl_ui[1], g_item[1], b_item[1], out_item,
        mean_user, w_user, Wb + 6 * 16384, Wb + 7 * 16384,
        bl_iu[1], g_user[1], b_user[1], out_user);
}

// Round 17
// 286.937 us; speedup vs baseline: 1.0530x; 1.0530x over previous
//
#include <hip/hip_runtime.h>

#define NN 100000
#define NE 600000
#define CC 128
#define CVB2 3125            // NN*CC / 4096 (conversion blocks per array)
#define AB 6250              // NN / 16 (nodes per agg block = 16)
#define GBD 782              // ceil(NN / 128)
#define NBK 49               // coarse buckets per graph (dst >> 11)
#define BCAP 16384           // slots per bucket (expected ~12245, 34 sigma margin)
#define EPB 2048             // edges per block in bucket pass
#define BBLK 293             // ceil(NE / EPB)

typedef __attribute__((ext_vector_type(8))) short short8v;
typedef __attribute__((ext_vector_type(8))) unsigned short ushort8v;
typedef __attribute__((ext_vector_type(4))) unsigned short ushort4v;
typedef __attribute__((ext_vector_type(4))) float float4v;

__device__ __forceinline__ unsigned short f2bf(float f) {
    union { float f; unsigned u; } c; c.f = f;
    unsigned r = c.u + 0x7FFFu + ((c.u >> 16) & 1u);   // RNE
    return (unsigned short)(r >> 16);
}
__device__ __forceinline__ float bf2f(unsigned short u) {
    union { unsigned u; float f; } c; c.u = (unsigned)u << 16;
    return c.f;
}
__device__ __forceinline__ void addu8(float4& lo, float4& hi, ushort8v u) {
    lo.x += bf2f(u[0]); lo.y += bf2f(u[1]); lo.z += bf2f(u[2]); lo.w += bf2f(u[3]);
    hi.x += bf2f(u[4]); hi.y += bf2f(u[5]); hi.z += bf2f(u[6]); hi.w += bf2f(u[7]);
}
__device__ __forceinline__ ushort8v cvt8(const float* p) {
    float4 a = *reinterpret_cast<const float4*>(p);
    float4 b = *reinterpret_cast<const float4*>(p + 4);
    ushort8v h;
    h[0] = f2bf(a.x); h[1] = f2bf(a.y); h[2] = f2bf(a.z); h[3] = f2bf(a.w);
    h[4] = f2bf(b.x); h[5] = f2bf(b.y); h[6] = f2bf(b.z); h[7] = f2bf(b.w);
    return h;
}

// ---- k_bucket: multisplit edges into 49 coarse dst-buckets per graph ----
// EPB=2048 (round-15 verified). cur[] zeroed by hipMemsetAsync.

__global__ __launch_bounds__(256)
void k_bucket(const int* __restrict__ ei0, const int* __restrict__ ei1,
              int* __restrict__ cur, int2* __restrict__ bkt) {
    __shared__ int hist[NBK];
    __shared__ int basew[NBK];
    int bid = blockIdx.x, t = threadIdx.x;
    int g = (bid >= BBLK) ? 1 : 0;
    const int* ei = g ? ei1 : ei0;
    int local = g ? bid - BBLK : bid;
    int e0 = local * EPB;
    int cnt = NE - e0; if (cnt > EPB) cnt = EPB;
    if (cnt <= 0) return;
    if (t < NBK) hist[t] = 0;
    __syncthreads();
    for (int i = t; i < cnt; i += 256)
        atomicAdd(&hist[ei[NE + e0 + i] >> 11], 1);
    __syncthreads();
    if (t < NBK) {
        basew[t] = atomicAdd(&cur[g * NBK + t], hist[t]);
        hist[t] = 0;
    }
    __syncthreads();
    int2* bg = bkt + (size_t)g * NBK * BCAP;
    for (int i = t; i < cnt; i += 256) {
        int dst = ei[NE + e0 + i];
        int src = ei[e0 + i];
        int b = dst >> 11;
        int r = atomicAdd(&hist[b], 1);
        int pos = basew[b] + r;
        if (pos < BCAP)
            bg[(size_t)b * BCAP + pos] = make_int2(src, dst);
    }
}

// ---- k_conv: x->bf16 (2 chunks/thread) + W->bf16 ----

__global__ __launch_bounds__(256)
void k_conv(const float* __restrict__ xu, const float* __restrict__ xi,
            unsigned short* __restrict__ xbu, unsigned short* __restrict__ xbi,
            const float* w0, const float* w1, const float* w2, const float* w3,
            const float* w4, const float* w5, const float* w6, const float* w7,
            unsigned short* __restrict__ Wb) {
    int bid = blockIdx.x, t = threadIdx.x;
    if (bid < 2 * CVB2) {
        const float* src = (bid < CVB2) ? xu : xi;
        unsigned short* dst = (bid < CVB2) ? xbu : xbi;
        int local = (bid < CVB2) ? bid : bid - CVB2;
        size_t idx = (size_t)local * 4096 + t * 8;
        ushort8v a = cvt8(src + idx);
        ushort8v b = cvt8(src + idx + 2048);
        *reinterpret_cast<ushort8v*>(dst + idx) = a;
        *reinterpret_cast<ushort8v*>(dst + idx + 2048) = b;
        return;
    }
    bid -= 2 * CVB2;
    int m = bid >> 3;
    const float* src = w0;
    if (m == 1) src = w1; else if (m == 2) src = w2; else if (m == 3) src = w3;
    else if (m == 4) src = w4; else if (m == 5) src = w5;
    else if (m == 6) src = w6; else if (m == 7) src = w7;
    size_t idx = (size_t)(bid & 7) * 2048 + t * 8;
    *reinterpret_cast<ushort8v*>(Wb + (size_t)m * 16384 + idx) = cvt8(src + idx);
}

// ---- k_csr: per-bucket counting sort -> padded CSR + rp/re ----

__global__ __launch_bounds__(256)
void k_csr(const int* __restrict__ cnts, const int2* __restrict__ bkt,
           int* __restrict__ rp0, int* __restrict__ re0,
           int* __restrict__ rp1, int* __restrict__ re1,
           int* __restrict__ csr) {
    __shared__ int deg[2048];
    __shared__ int curp[2048];
    __shared__ int s[256];
    int bid = blockIdx.x;
    int g = (bid >= NBK) ? 1 : 0;
    int bb = g ? bid - NBK : bid;
    int t = threadIdx.x;
    const int2* eb = bkt + (size_t)(g * NBK + bb) * BCAP;
    int cnt = cnts[g * NBK + bb];
    if (cnt > BCAP) cnt = BCAP;
    int dbase = bb * 2048;
    int cb = (g * NBK + bb) * BCAP;
    int* rp = g ? rp1 : rp0;
    int* re = g ? re1 : re0;
    for (int i = t; i < 2048; i += 256) deg[i] = 0;
    __syncthreads();
    for (int i = t; i < cnt; i += 256) {
        int2 e = eb[i];
        atomicAdd(&deg[e.y - dbase], 1);
    }
    __syncthreads();
    int loc[8]; int v = 0; int b8 = t * 8;
#pragma unroll
    for (int u = 0; u < 8; ++u) { loc[u] = deg[b8 + u]; v += loc[u]; }
    s[t] = v; __syncthreads();
    for (int off = 1; off < 256; off <<= 1) {
        int x = (t >= off) ? s[t - off] : 0;
        __syncthreads();
        s[t] += x;
        __syncthreads();
    }
    int run = s[t] - v;
#pragma unroll
    for (int u = 0; u < 8; ++u) {
        int d = b8 + u;
        int gd = dbase + d;
        int start = cb + run;
        curp[d] = start;
        if (gd < NN) { rp[gd] = start; re[gd] = start + loc[u]; }
        run += loc[u];
    }
    __syncthreads();
    for (int i = t; i < cnt; i += 256) {
        int2 e = eb[i];
        int p = atomicAdd(&curp[e.y - dbase], 1);
        csr[p] = e.x;
    }
}

// ------------- aggregation (both directions in one launch), bf16 -------------

__global__ __launch_bounds__(256)
void k_agg2(const unsigned short* __restrict__ s0, const int* __restrict__ rp0,
            const int* __restrict__ re0, unsigned short* __restrict__ m0,
            const unsigned short* __restrict__ s1, const int* __restrict__ rp1,
            const int* __restrict__ re1, unsigned short* __restrict__ m1,
            const int* __restrict__ csr) {
    int bid = blockIdx.x;
    const unsigned short* src; const int* rp; const int* re; unsigned short* mean;
    if (bid < AB) { src = s0; rp = rp0; re = re0; mean = m0; }
    else { bid -= AB; src = s1; rp = rp1; re = re1; mean = m1; }
    int t = threadIdx.x;
    int node = bid * 16 + (t >> 4);
    int j0 = (t & 15) * 8;
    int b = rp[node], e = re[node];
    float4 z = make_float4(0.f, 0.f, 0.f, 0.f);
    float4 l0 = z, h0 = z, l1 = z, h1 = z, l2 = z, h2 = z, l3 = z, h3 = z;
    int i = b;
    for (; i + 4 <= e; i += 4) {
        int a = csr[i], bb = csr[i + 1], c = csr[i + 2], d = csr[i + 3];
        ushort8v u0 = *reinterpret_cast<const ushort8v*>(src + (size_t)a * CC + j0);
        ushort8v u1 = *reinterpret_cast<const ushort8v*>(src + (size_t)bb * CC + j0);
        ushort8v u2 = *reinterpret_cast<const ushort8v*>(src + (size_t)c * CC + j0);
        ushort8v u3 = *reinterpret_cast<const ushort8v*>(src + (size_t)d * CC + j0);
        addu8(l0, h0, u0); addu8(l1, h1, u1); addu8(l2, h2, u2); addu8(l3, h3, u3);
    }
    for (; i + 2 <= e; i += 2) {
        int a = csr[i], bb = csr[i + 1];
        ushort8v u0 = *reinterpret_cast<const ushort8v*>(src + (size_t)a * CC + j0);
        ushort8v u1 = *reinterpret_cast<const ushort8v*>(src + (size_t)bb * CC + j0);
        addu8(l0, h0, u0); addu8(l1, h1, u1);
    }
    if (i < e) {
        int a = csr[i];
        addu8(l0, h0, *reinterpret_cast<const ushort8v*>(src + (size_t)a * CC + j0));
    }
    int dg = e - b;
    float inv = 1.f / (float)(dg > 1 ? dg : 1);
    float m_[8];
    m_[0] = ((l0.x + l1.x) + (l2.x + l3.x)) * inv;
    m_[1] = ((l0.y + l1.y) + (l2.y + l3.y)) * inv;
    m_[2] = ((l0.z + l1.z) + (l2.z + l3.z)) * inv;
    m_[3] = ((l0.w + l1.w) + (l2.w + l3.w)) * inv;
    m_[4] = ((h0.x + h1.x) + (h2.x + h3.x)) * inv;
    m_[5] = ((h0.y + h1.y) + (h2.y + h3.y)) * inv;
    m_[6] = ((h0.z + h1.z) + (h2.z + h3.z)) * inv;
    m_[7] = ((h0.w + h1.w) + (h2.w + h3.w)) * inv;
    ushort8v h;
#pragma unroll
    for (int k = 0; k < 8; ++k) h[k] = f2bf(m_[k]);
    *reinterpret_cast<ushort8v*>(mean + (size_t)node * CC + j0) = h;
}

// ------- MFMA fused GEMM+LN+ReLU, both directions in one launch -------
// Round-12 verified structure: 1024 thr = 16 waves (2 mg x 8 ng), tile 128x128,
// K=256, all-bf16, hoisted Wl fragments, LN epilogue under t < 512.

template<bool OUTF32>
__global__ __launch_bounds__(1024, 4)
void k_gemm2(const unsigned short* __restrict__ mean0, const unsigned short* __restrict__ x0,
             const unsigned short* __restrict__ wl0, const unsigned short* __restrict__ wr0,
             const float* __restrict__ bl0, const float* __restrict__ g0,
             const float* __restrict__ bb0, void* __restrict__ out0,
             const unsigned short* __restrict__ mean1, const unsigned short* __restrict__ x1,
             const unsigned short* __restrict__ wl1, const unsigned short* __restrict__ wr1,
             const float* __restrict__ bl1, const float* __restrict__ g1,
             const float* __restrict__ bb1, void* __restrict__ out1) {
    __shared__ char sA[128 * 512];              // 64 KB bf16 A tile, then fp32 LN buf
    __shared__ float sbl[128], sg[128], sb[128];

    int bid = blockIdx.x;
    const unsigned short *mean, *xs, *wl, *wr;
    const float *bl, *g, *bb;
    void* out;
    if (bid < GBD) { mean = mean0; xs = x0; wl = wl0; wr = wr0; bl = bl0; g = g0; bb = bb0; out = out0; }
    else { bid -= GBD; mean = mean1; xs = x1; wl = wl1; wr = wr1; bl = bl1; g = g1; bb = bb1; out = out1; }

    int t = threadIdx.x;
    int base = bid * 128;
    if (t < 128) { sbl[t] = bl[t]; sg[t] = g[t]; sb[t] = bb[t]; }

    int wid = t >> 6, l = t & 63;
    int mg = wid >> 3, ng = wid & 7;        // 2 mg x 8 ng
    int l15 = l & 15, l4 = l >> 4;

    // ---- hoisted: khalf=0 (Wl) B-fragments, issued before staging ----
    short8v bf0[4];
    {
        int j = ng * 16 + l15;
        const unsigned short* wrow = wl + (size_t)j * CC + l4 * 8;
#pragma unroll
        for (int kk4 = 0; kk4 < 4; ++kk4)
            bf0[kk4] = *reinterpret_cast<const short8v*>(wrow + kk4 * 32);
    }

    // ---- stage A tile (both halves bf16): 8 threads/row ----
    {
        int r = t >> 3, q = t & 7;
        int swz = (r & 7) << 4;
        int node = base + r;
        bool valid = node < NN;
        const unsigned short* mrow = mean + (size_t)node * CC;
        const unsigned short* xrow = xs + (size_t)node * CC;
        ushort8v zz = (ushort8v){0, 0, 0, 0, 0, 0, 0, 0};
#pragma unroll
        for (int j = 0; j < 2; ++j) {
            int col = (j * 8 + q) * 8;
            ushort8v hm = valid ? *reinterpret_cast<const ushort8v*>(mrow + col) : zz;
            *reinterpret_cast<ushort8v*>(sA + ((r * 512 + col * 2) ^ swz)) = hm;
            ushort8v hx = valid ? *reinterpret_cast<const ushort8v*>(xrow + col) : zz;
            *reinterpret_cast<ushort8v*>(sA + ((r * 512 + 256 + col * 2) ^ swz)) = hx;
        }
    }
    __syncthreads();

    float4v acc[4];
#pragma unroll
    for (int mt = 0; mt < 4; ++mt)
        acc[mt] = (float4v){0.f, 0.f, 0.f, 0.f};

    // ---- khalf = 0 (mean half, Wl) ----
#pragma unroll
    for (int kk4 = 0; kk4 < 4; ++kk4) {
        short8v af[4];
#pragma unroll
        for (int mt = 0; mt < 4; ++mt) {
            int row = mg * 64 + mt * 16 + l15;
            int byte = (row * 512 + l4 * 16 + kk4 * 64) ^ ((row & 7) << 4);
            af[mt] = *reinterpret_cast<short8v*>(sA + byte);
        }
#pragma unroll
        for (int mt = 0; mt < 4; ++mt)
            acc[mt] = __builtin_amdgcn_mfma_f32_16x16x32_bf16(
                af[mt], bf0[kk4], acc[mt], 0, 0, 0);
    }

    // ---- khalf = 1 (x half, Wr) ----
    {
        short8v bf1[4];
        {
            int j = ng * 16 + l15;
            const unsigned short* wrow = wr + (size_t)j * CC + l4 * 8;
#pragma unroll
            for (int kk4 = 0; kk4 < 4; ++kk4)
                bf1[kk4] = *reinterpret_cast<const short8v*>(wrow + kk4 * 32);
        }
#pragma unroll
        for (int kk4 = 0; kk4 < 4; ++kk4) {
            short8v af[4];
#pragma unroll
            for (int mt = 0; mt < 4; ++mt) {
                int row = mg * 64 + mt * 16 + l15;
                int byte = (row * 512 + l4 * 16 + (4 + kk4) * 64) ^ ((row & 7) << 4);
                af[mt] = *reinterpret_cast<short8v*>(sA + byte);
            }
#pragma unroll
            for (int mt = 0; mt < 4; ++mt)
                acc[mt] = __builtin_amdgcn_mfma_f32_16x16x32_bf16(
                    af[mt], bf1[kk4], acc[mt], 0, 0, 0);
        }
    }
    __syncthreads();   // A tile free; reuse as fp32 LN buffer

    // ---- scatter biased acc -> LDS fp32 (same swizzle) ----
#pragma unroll
    for (int mt = 0; mt < 4; ++mt)
#pragma unroll
        for (int r4 = 0; r4 < 4; ++r4) {
            int nrow = mg * 64 + mt * 16 + l4 * 4 + r4;
            int col = ng * 16 + l15;
            float v = acc[mt][r4] + sbl[col];
            int byte = (nrow * 512 + col * 4) ^ ((nrow & 7) << 4);
            *reinterpret_cast<float*>(sA + byte) = v;
        }
    __syncthreads();

    // ---- transposed LN + ReLU + store (verbatim round-7 path, t < 512) ----
    if (t < 512) {
        int nn_ = t >> 2, qq = t & 3;
        int gnode = base + nn_;
        float s1 = 0.f, s2 = 0.f;
        float4 vv[8];
#pragma unroll
        for (int u = 0; u < 8; ++u) {
            int c = qq * 4 + u * 16;
            int byte = (nn_ * 512 + c * 4) ^ ((nn_ & 7) << 4);
            float4 vx = *reinterpret_cast<float4*>(sA + byte);
            vv[u] = vx;
            s1 += vx.x + vx.y + vx.z + vx.w;
            s2 += vx.x * vx.x + vx.y * vx.y + vx.z * vx.z + vx.w * vx.w;
        }
        s1 += __shfl_xor(s1, 1); s1 += __shfl_xor(s1, 2);
        s2 += __shfl_xor(s2, 1); s2 += __shfl_xor(s2, 2);
        float mu = s1 * (1.f / 128.f);
        float var = s2 * (1.f / 128.f) - mu * mu;
        float rstd = rsqrtf(var + 1e-5f);
        if (gnode < NN) {
#pragma unroll
            for (int u = 0; u < 8; ++u) {
                int c = qq * 4 + u * 16;
                float4 vx = vv[u];
                float4 o;
                o.x = fmaxf(0.f, (vx.x - mu) * rstd * sg[c + 0] + sb[c + 0]);
                o.y = fmaxf(0.f, (vx.y - mu) * rstd * sg[c + 1] + sb[c + 1]);
                o.z = fmaxf(0.f, (vx.z - mu) * rstd * sg[c + 2] + sb[c + 2]);
                o.w = fmaxf(0.f, (vx.w - mu) * rstd * sg[c + 3] + sb[c + 3]);
                if (OUTF32) {
                    float* op = (float*)out + (size_t)gnode * CC;
                    *reinterpret_cast<float4*>(op + c) = o;
                } else {
                    unsigned short* op = (unsigned short*)out + (size_t)gnode * CC;
                    ushort4v h; h.x = f2bf(o.x); h.y = f2bf(o.y); h.z = f2bf(o.z); h.w = f2bf(o.w);
                    *reinterpret_cast<ushort4v*>(op + c) = h;
                }
            }
        }
    }
}

// ---------------- launch ----------------

extern "C" void kernel_launch(void* const* d_in, const int* in_sizes, int n_in,
                              void* d_out, int out_size, void* d_ws, size_t ws_size,
                              hipStream_t stream) {
    const float* x_user = (const float*)d_in[0];
    const float* x_item = (const float*)d_in[1];
    const int* ei_ui = (const int*)d_in[2];
    const int* ei_iu = (const int*)d_in[3];

    const float* Wl_ui[2] = {(const float*)d_in[4],  (const float*)d_in[14]};
    const float* bl_ui[2] = {(const float*)d_in[5],  (const float*)d_in[15]};
    const float* Wr_ui[2] = {(const float*)d_in[6],  (const float*)d_in[16]};
    const float* Wl_iu[2] = {(const float*)d_in[7],  (const float*)d_in[17]};
    const float* bl_iu[2] = {(const float*)d_in[8],  (const float*)d_in[18]};
    const float* Wr_iu[2] = {(const float*)d_in[9],  (const float*)d_in[19]};
    const float* g_user[2] = {(const float*)d_in[10], (const float*)d_in[20]};
    const float* b_user[2] = {(const float*)d_in[11], (const float*)d_in[21]};
    const float* g_item[2] = {(const float*)d_in[12], (const float*)d_in[22]};
    const float* b_item[2] = {(const float*)d_in[13], (const float*)d_in[23]};

    auto align = [](size_t x) { return (x + 255) & ~(size_t)255; };
    char* w = (char*)d_ws;
    int* cur = (int*)w; w += align((size_t)2 * NBK * 4);
    int2* bkt = (int2*)w; w += align((size_t)2 * NBK * BCAP * 8);
    int* csr = (int*)w; w += align((size_t)2 * NBK * BCAP * 4);
    int* rp_ui = (int*)w; w += align((size_t)NN * 4);
    int* re_ui = (int*)w; w += align((size_t)NN * 4);
    int* rp_iu = (int*)w; w += align((size_t)NN * 4);
    int* re_iu = (int*)w; w += align((size_t)NN * 4);
    unsigned short* Wb = (unsigned short*)w; w += align((size_t)8 * 16384 * 2);
    unsigned short* xb_user = (unsigned short*)w; w += align((size_t)NN * CC * 2);
    unsigned short* xb_item = (unsigned short*)w; w += align((size_t)NN * CC * 2);
    unsigned short* w_user = (unsigned short*)w; w += align((size_t)NN * CC * 2);
    unsigned short* w_item = (unsigned short*)w; w += align((size_t)NN * CC * 2);
    unsigned short* mean_item = (unsigned short*)w; w += align((size_t)NN * CC * 2);
    unsigned short* mean_user = (unsigned short*)w; w += align((size_t)NN * CC * 2);

    float* out_user = (float*)d_out;
    float* out_item = (float*)d_out + (size_t)NN * CC;

    // ---- cursors -> 0; bucketing, conversions, CSR (split for attribution) ----
    hipMemsetAsync(cur, 0, (size_t)(2 * NBK) * sizeof(int), stream);
    k_bucket<<<2 * BBLK, 256, 0, stream>>>(ei_ui, ei_iu, cur, bkt);
    k_conv<<<2 * CVB2 + 64, 256, 0, stream>>>(
        x_user, x_item, xb_user, xb_item,
        Wl_ui[0], Wr_ui[0], Wl_iu[0], Wr_iu[0],
        Wl_ui[1], Wr_ui[1], Wl_iu[1], Wr_iu[1], Wb);
    k_csr<<<2 * NBK, 256, 0, stream>>>(cur, bkt, rp_ui, re_ui, rp_iu, re_iu, csr);

    // ---- layer 0 (all bf16) ----
    k_agg2<<<2 * AB, 256, 0, stream>>>(xb_user, rp_ui, re_ui, mean_item,
                                       xb_item, rp_iu, re_iu, mean_user, csr);
    k_gemm2<false><<<2 * GBD, 1024, 0, stream>>>(
        mean_item, xb_item, Wb + 0 * 16384, Wb + 1 * 16384,
        bl_ui[0], g_item[0], b_item[0], w_item,
        mean_user, xb_user, Wb + 2 * 16384, Wb + 3 * 16384,
        bl_iu[0], g_user[0], b_user[0], w_user);

    // ---- layer 1 (all bf16) ----
    k_agg2<<<2 * AB, 256, 0, stream>>>(w_user, rp_ui, re_ui, mean_item,
                                       w_item, rp_iu, re_iu, mean_user, csr);
    k_gemm2<true><<<2 * GBD, 1024, 0, stream>>>(
        mean_item, w_item, Wb + 4 * 16384, Wb + 5 * 16384,
        bl_ui[1], g_item[1], b_item[1], out_item,
        mean_user, w_user, Wb + 6 * 16384, Wb + 7 * 16384,
        bl_iu[1], g_user[1], b_user[1], out_user);
}

// Round 18
// 276.528 us; speedup vs baseline: 1.0926x; 1.0376x over previous
//
#include <hip/hip_runtime.h>

#define NN 100000
#define NE 600000
#define CC 128
#define CVB2 3125            // NN*CC / 4096 (conversion blocks per array)
#define AB 6250              // NN / 16 (nodes per agg block = 16)
#define GBD 782              // ceil(NN / 128)
#define NBK 49               // coarse buckets per graph (dst >> 11)
#define BCAP 16384           // slots per bucket (expected ~12245, 34 sigma margin)
#define EPB 2048             // edges per block in bucket pass
#define BBLK 293             // ceil(NE / EPB)

typedef __attribute__((ext_vector_type(8))) short short8v;
typedef __attribute__((ext_vector_type(8))) unsigned short ushort8v;
typedef __attribute__((ext_vector_type(4))) unsigned short ushort4v;
typedef __attribute__((ext_vector_type(4))) float float4v;

__device__ __forceinline__ unsigned short f2bf(float f) {
    union { float f; unsigned u; } c; c.f = f;
    unsigned r = c.u + 0x7FFFu + ((c.u >> 16) & 1u);   // RNE
    return (unsigned short)(r >> 16);
}
__device__ __forceinline__ float bf2f(unsigned short u) {
    union { unsigned u; float f; } c; c.u = (unsigned)u << 16;
    return c.f;
}
__device__ __forceinline__ void addu8(float4& lo, float4& hi, ushort8v u) {
    lo.x += bf2f(u[0]); lo.y += bf2f(u[1]); lo.z += bf2f(u[2]); lo.w += bf2f(u[3]);
    hi.x += bf2f(u[4]); hi.y += bf2f(u[5]); hi.z += bf2f(u[6]); hi.w += bf2f(u[7]);
}
__device__ __forceinline__ ushort8v cvt8(const float* p) {
    float4 a = *reinterpret_cast<const float4*>(p);
    float4 b = *reinterpret_cast<const float4*>(p + 4);
    ushort8v h;
    h[0] = f2bf(a.x); h[1] = f2bf(a.y); h[2] = f2bf(a.z); h[3] = f2bf(a.w);
    h[4] = f2bf(b.x); h[5] = f2bf(b.y); h[6] = f2bf(b.z); h[7] = f2bf(b.w);
    return h;
}

// ---- k_preall: edge bucketing (both graphs) + x->bf16 + W->bf16, one launch.
// cur[] zeroed by hipMemsetAsync before this launch.
// EPB=2048 (short bucket blocks -> small tail); conversion blocks do
// 2 chunks/thread (2x MLP).

__global__ __launch_bounds__(256)
void k_preall(const int* __restrict__ ei0, const int* __restrict__ ei1,
              int* __restrict__ cur, int2* __restrict__ bkt,
              const float* __restrict__ xu, const float* __restrict__ xi,
              unsigned short* __restrict__ xbu, unsigned short* __restrict__ xbi,
              const float* w0, const float* w1, const float* w2, const float* w3,
              const float* w4, const float* w5, const float* w6, const float* w7,
              unsigned short* __restrict__ Wb) {
    __shared__ int hist[NBK];
    __shared__ int basew[NBK];
    int bid = blockIdx.x, t = threadIdx.x;
    if (bid < 2 * BBLK) {
        int g = (bid >= BBLK) ? 1 : 0;
        const int* ei = g ? ei1 : ei0;
        int local = g ? bid - BBLK : bid;
        int e0 = local * EPB;
        int cnt = NE - e0; if (cnt > EPB) cnt = EPB;
        if (cnt <= 0) return;
        if (t < NBK) hist[t] = 0;
        __syncthreads();
        for (int i = t; i < cnt; i += 256)
            atomicAdd(&hist[ei[NE + e0 + i] >> 11], 1);
        __syncthreads();
        if (t < NBK) {
            basew[t] = atomicAdd(&cur[g * NBK + t], hist[t]);
            hist[t] = 0;
        }
        __syncthreads();
        int2* bg = bkt + (size_t)g * NBK * BCAP;
        for (int i = t; i < cnt; i += 256) {
            int dst = ei[NE + e0 + i];
            int src = ei[e0 + i];
            int b = dst >> 11;
            int r = atomicAdd(&hist[b], 1);
            int pos = basew[b] + r;
            if (pos < BCAP)
                bg[(size_t)b * BCAP + pos] = make_int2(src, dst);
        }
        return;
    }
    bid -= 2 * BBLK;
    if (bid < 2 * CVB2) {
        const float* src = (bid < CVB2) ? xu : xi;
        unsigned short* dst = (bid < CVB2) ? xbu : xbi;
        int local = (bid < CVB2) ? bid : bid - CVB2;
        size_t idx = (size_t)local * 4096 + t * 8;
        ushort8v a = cvt8(src + idx);
        ushort8v b = cvt8(src + idx + 2048);
        *reinterpret_cast<ushort8v*>(dst + idx) = a;
        *reinterpret_cast<ushort8v*>(dst + idx + 2048) = b;
        return;
    }
    bid -= 2 * CVB2;
    int m = bid >> 3;
    const float* src = w0;
    if (m == 1) src = w1; else if (m == 2) src = w2; else if (m == 3) src = w3;
    else if (m == 4) src = w4; else if (m == 5) src = w5;
    else if (m == 6) src = w6; else if (m == 7) src = w7;
    size_t idx = (size_t)(bid & 7) * 2048 + t * 8;
    *reinterpret_cast<ushort8v*>(Wb + (size_t)m * 16384 + idx) = cvt8(src + idx);
}

// ---- k_csr: per-bucket counting sort -> padded CSR + rp/re ----

__global__ __launch_bounds__(256)
void k_csr(const int* __restrict__ cnts, const int2* __restrict__ bkt,
           int* __restrict__ rp0, int* __restrict__ re0,
           int* __restrict__ rp1, int* __restrict__ re1,
           int* __restrict__ csr) {
    __shared__ int deg[2048];
    __shared__ int curp[2048];
    __shared__ int s[256];
    int bid = blockIdx.x;
    int g = (bid >= NBK) ? 1 : 0;
    int bb = g ? bid - NBK : bid;
    int t = threadIdx.x;
    const int2* eb = bkt + (size_t)(g * NBK + bb) * BCAP;
    int cnt = cnts[g * NBK + bb];
    if (cnt > BCAP) cnt = BCAP;
    int dbase = bb * 2048;
    int cb = (g * NBK + bb) * BCAP;
    int* rp = g ? rp1 : rp0;
    int* re = g ? re1 : re0;
    for (int i = t; i < 2048; i += 256) deg[i] = 0;
    __syncthreads();
    for (int i = t; i < cnt; i += 256) {
        int2 e = eb[i];
        atomicAdd(&deg[e.y - dbase], 1);
    }
    __syncthreads();
    int loc[8]; int v = 0; int b8 = t * 8;
#pragma unroll
    for (int u = 0; u < 8; ++u) { loc[u] = deg[b8 + u]; v += loc[u]; }
    s[t] = v; __syncthreads();
    for (int off = 1; off < 256; off <<= 1) {
        int x = (t >= off) ? s[t - off] : 0;
        __syncthreads();
        s[t] += x;
        __syncthreads();
    }
    int run = s[t] - v;
#pragma unroll
    for (int u = 0; u < 8; ++u) {
        int d = b8 + u;
        int gd = dbase + d;
        int start = cb + run;
        curp[d] = start;
        if (gd < NN) { rp[gd] = start; re[gd] = start + loc[u]; }
        run += loc[u];
    }
    __syncthreads();
    for (int i = t; i < cnt; i += 256) {
        int2 e = eb[i];
        int p = atomicAdd(&curp[e.y - dbase], 1);
        csr[p] = e.x;
    }
}

// ------------- aggregation (both directions in one launch), bf16 -------------

__global__ __launch_bounds__(256)
void k_agg2(const unsigned short* __restrict__ s0, const int* __restrict__ rp0,
            const int* __restrict__ re0, unsigned short* __restrict__ m0,
            const unsigned short* __restrict__ s1, const int* __restrict__ rp1,
            const int* __restrict__ re1, unsigned short* __restrict__ m1,
            const int* __restrict__ csr) {
    int bid = blockIdx.x;
    const unsigned short* src; const int* rp; const int* re; unsigned short* mean;
    if (bid < AB) { src = s0; rp = rp0; re = re0; mean = m0; }
    else { bid -= AB; src = s1; rp = rp1; re = re1; mean = m1; }
    int t = threadIdx.x;
    int node = bid * 16 + (t >> 4);
    int j0 = (t & 15) * 8;
    int b = rp[node], e = re[node];
    float4 z = make_float4(0.f, 0.f, 0.f, 0.f);
    float4 l0 = z, h0 = z, l1 = z, h1 = z, l2 = z, h2 = z, l3 = z, h3 = z;
    int i = b;
    for (; i + 4 <= e; i += 4) {
        int a = csr[i], bb = csr[i + 1], c = csr[i + 2], d = csr[i + 3];
        ushort8v u0 = *reinterpret_cast<const ushort8v*>(src + (size_t)a * CC + j0);
        ushort8v u1 = *reinterpret_cast<const ushort8v*>(src + (size_t)bb * CC + j0);
        ushort8v u2 = *reinterpret_cast<const ushort8v*>(src + (size_t)c * CC + j0);
        ushort8v u3 = *reinterpret_cast<const ushort8v*>(src + (size_t)d * CC + j0);
        addu8(l0, h0, u0); addu8(l1, h1, u1); addu8(l2, h2, u2); addu8(l3, h3, u3);
    }
    for (; i + 2 <= e; i += 2) {
        int a = csr[i], bb = csr[i + 1];
        ushort8v u0 = *reinterpret_cast<const ushort8v*>(src + (size_t)a * CC + j0);
        ushort8v u1 = *reinterpret_cast<const ushort8v*>(src + (size_t)bb * CC + j0);
        addu8(l0, h0, u0); addu8(l1, h1, u1);
    }
    if (i < e) {
        int a = csr[i];
        addu8(l0, h0, *reinterpret_cast<const ushort8v*>(src + (size_t)a * CC + j0));
    }
    int dg = e - b;
    float inv = 1.f / (float)(dg > 1 ? dg : 1);
    float m_[8];
    m_[0] = ((l0.x + l1.x) + (l2.x + l3.x)) * inv;
    m_[1] = ((l0.y + l1.y) + (l2.y + l3.y)) * inv;
    m_[2] = ((l0.z + l1.z) + (l2.z + l3.z)) * inv;
    m_[3] = ((l0.w + l1.w) + (l2.w + l3.w)) * inv;
    m_[4] = ((h0.x + h1.x) + (h2.x + h3.x)) * inv;
    m_[5] = ((h0.y + h1.y) + (h2.y + h3.y)) * inv;
    m_[6] = ((h0.z + h1.z) + (h2.z + h3.z)) * inv;
    m_[7] = ((h0.w + h1.w) + (h2.w + h3.w)) * inv;
    ushort8v h;
#pragma unroll
    for (int k = 0; k < 8; ++k) h[k] = f2bf(m_[k]);
    *reinterpret_cast<ushort8v*>(mean + (size_t)node * CC + j0) = h;
}

// ------- MFMA fused GEMM+LN+ReLU, both directions in one launch -------
// Round-12 verified structure: 1024 thr = 16 waves (2 mg x 8 ng), tile 128x128,
// K=256, all-bf16, hoisted Wl fragments, LN epilogue under t < 512.

template<bool OUTF32>
__global__ __launch_bounds__(1024, 4)
void k_gemm2(const unsigned short* __restrict__ mean0, const unsigned short* __restrict__ x0,
             const unsigned short* __restrict__ wl0, const unsigned short* __restrict__ wr0,
             const float* __restrict__ bl0, const float* __restrict__ g0,
             const float* __restrict__ bb0, void* __restrict__ out0,
             const unsigned short* __restrict__ mean1, const unsigned short* __restrict__ x1,
             const unsigned short* __restrict__ wl1, const unsigned short* __restrict__ wr1,
             const float* __restrict__ bl1, const float* __restrict__ g1,
             const float* __restrict__ bb1, void* __restrict__ out1) {
    __shared__ char sA[128 * 512];              // 64 KB bf16 A tile, then fp32 LN buf
    __shared__ float sbl[128], sg[128], sb[128];

    int bid = blockIdx.x;
    const unsigned short *mean, *xs, *wl, *wr;
    const float *bl, *g, *bb;
    void* out;
    if (bid < GBD) { mean = mean0; xs = x0; wl = wl0; wr = wr0; bl = bl0; g = g0; bb = bb0; out = out0; }
    else { bid -= GBD; mean = mean1; xs = x1; wl = wl1; wr = wr1; bl = bl1; g = g1; bb = bb1; out = out1; }

    int t = threadIdx.x;
    int base = bid * 128;
    if (t < 128) { sbl[t] = bl[t]; sg[t] = g[t]; sb[t] = bb[t]; }

    int wid = t >> 6, l = t & 63;
    int mg = wid >> 3, ng = wid & 7;        // 2 mg x 8 ng
    int l15 = l & 15, l4 = l >> 4;

    // ---- hoisted: khalf=0 (Wl) B-fragments, issued before staging ----
    short8v bf0[4];
    {
        int j = ng * 16 + l15;
        const unsigned short* wrow = wl + (size_t)j * CC + l4 * 8;
#pragma unroll
        for (int kk4 = 0; kk4 < 4; ++kk4)
            bf0[kk4] = *reinterpret_cast<const short8v*>(wrow + kk4 * 32);
    }

    // ---- stage A tile (both halves bf16): 8 threads/row ----
    {
        int r = t >> 3, q = t & 7;
        int swz = (r & 7) << 4;
        int node = base + r;
        bool valid = node < NN;
        const unsigned short* mrow = mean + (size_t)node * CC;
        const unsigned short* xrow = xs + (size_t)node * CC;
        ushort8v zz = (ushort8v){0, 0, 0, 0, 0, 0, 0, 0};
#pragma unroll
        for (int j = 0; j < 2; ++j) {
            int col = (j * 8 + q) * 8;
            ushort8v hm = valid ? *reinterpret_cast<const ushort8v*>(mrow + col) : zz;
            *reinterpret_cast<ushort8v*>(sA + ((r * 512 + col * 2) ^ swz)) = hm;
            ushort8v hx = valid ? *reinterpret_cast<const ushort8v*>(xrow + col) : zz;
            *reinterpret_cast<ushort8v*>(sA + ((r * 512 + 256 + col * 2) ^ swz)) = hx;
        }
    }
    __syncthreads();

    float4v acc[4];
#pragma unroll
    for (int mt = 0; mt < 4; ++mt)
        acc[mt] = (float4v){0.f, 0.f, 0.f, 0.f};

    // ---- khalf = 0 (mean half, Wl) ----
#pragma unroll
    for (int kk4 = 0; kk4 < 4; ++kk4) {
        short8v af[4];
#pragma unroll
        for (int mt = 0; mt < 4; ++mt) {
            int row = mg * 64 + mt * 16 + l15;
            int byte = (row * 512 + l4 * 16 + kk4 * 64) ^ ((row & 7) << 4);
            af[mt] = *reinterpret_cast<short8v*>(sA + byte);
        }
#pragma unroll
        for (int mt = 0; mt < 4; ++mt)
            acc[mt] = __builtin_amdgcn_mfma_f32_16x16x32_bf16(
                af[mt], bf0[kk4], acc[mt], 0, 0, 0);
    }

    // ---- khalf = 1 (x half, Wr) ----
    {
        short8v bf1[4];
        {
            int j = ng * 16 + l15;
            const unsigned short* wrow = wr + (size_t)j * CC + l4 * 8;
#pragma unroll
            for (int kk4 = 0; kk4 < 4; ++kk4)
                bf1[kk4] = *reinterpret_cast<const short8v*>(wrow + kk4 * 32);
        }
#pragma unroll
        for (int kk4 = 0; kk4 < 4; ++kk4) {
            short8v af[4];
#pragma unroll
            for (int mt = 0; mt < 4; ++mt) {
                int row = mg * 64 + mt * 16 + l15;
                int byte = (row * 512 + l4 * 16 + (4 + kk4) * 64) ^ ((row & 7) << 4);
                af[mt] = *reinterpret_cast<short8v*>(sA + byte);
            }
#pragma unroll
            for (int mt = 0; mt < 4; ++mt)
                acc[mt] = __builtin_amdgcn_mfma_f32_16x16x32_bf16(
                    af[mt], bf1[kk4], acc[mt], 0, 0, 0);
        }
    }
    __syncthreads();   // A tile free; reuse as fp32 LN buffer

    // ---- scatter biased acc -> LDS fp32 (same swizzle) ----
#pragma unroll
    for (int mt = 0; mt < 4; ++mt)
#pragma unroll
        for (int r4 = 0; r4 < 4; ++r4) {
            int nrow = mg * 64 + mt * 16 + l4 * 4 + r4;
            int col = ng * 16 + l15;
            float v = acc[mt][r4] + sbl[col];
            int byte = (nrow * 512 + col * 4) ^ ((nrow & 7) << 4);
            *reinterpret_cast<float*>(sA + byte) = v;
        }
    __syncthreads();

    // ---- transposed LN + ReLU + store (verbatim round-7 path, t < 512) ----
    if (t < 512) {
        int nn_ = t >> 2, qq = t & 3;
        int gnode = base + nn_;
        float s1 = 0.f, s2 = 0.f;
        float4 vv[8];
#pragma unroll
        for (int u = 0; u < 8; ++u) {
            int c = qq * 4 + u * 16;
            int byte = (nn_ * 512 + c * 4) ^ ((nn_ & 7) << 4);
            float4 vx = *reinterpret_cast<float4*>(sA + byte);
            vv[u] = vx;
            s1 += vx.x + vx.y + vx.z + vx.w;
            s2 += vx.x * vx.x + vx.y * vx.y + vx.z * vx.z + vx.w * vx.w;
        }
        s1 += __shfl_xor(s1, 1); s1 += __shfl_xor(s1, 2);
        s2 += __shfl_xor(s2, 1); s2 += __shfl_xor(s2, 2);
        float mu = s1 * (1.f / 128.f);
        float var = s2 * (1.f / 128.f) - mu * mu;
        float rstd = rsqrtf(var + 1e-5f);
        if (gnode < NN) {
#pragma unroll
            for (int u = 0; u < 8; ++u) {
                int c = qq * 4 + u * 16;
                float4 vx = vv[u];
                float4 o;
                o.x = fmaxf(0.f, (vx.x - mu) * rstd * sg[c + 0] + sb[c + 0]);
                o.y = fmaxf(0.f, (vx.y - mu) * rstd * sg[c + 1] + sb[c + 1]);
                o.z = fmaxf(0.f, (vx.z - mu) * rstd * sg[c + 2] + sb[c + 2]);
                o.w = fmaxf(0.f, (vx.w - mu) * rstd * sg[c + 3] + sb[c + 3]);
                if (OUTF32) {
                    float* op = (float*)out + (size_t)gnode * CC;
                    *reinterpret_cast<float4*>(op + c) = o;
                } else {
                    unsigned short* op = (unsigned short*)out + (size_t)gnode * CC;
                    ushort4v h; h.x = f2bf(o.x); h.y = f2bf(o.y); h.z = f2bf(o.z); h.w = f2bf(o.w);
                    *reinterpret_cast<ushort4v*>(op + c) = h;
                }
            }
        }
    }
}

// ---------------- launch ----------------

extern "C" void kernel_launch(void* const* d_in, const int* in_sizes, int n_in,
                              void* d_out, int out_size, void* d_ws, size_t ws_size,
                              hipStream_t stream) {
    const float* x_user = (const float*)d_in[0];
    const float* x_item = (const float*)d_in[1];
    const int* ei_ui = (const int*)d_in[2];
    const int* ei_iu = (const int*)d_in[3];

    const float* Wl_ui[2] = {(const float*)d_in[4],  (const float*)d_in[14]};
    const float* bl_ui[2] = {(const float*)d_in[5],  (const float*)d_in[15]};
    const float* Wr_ui[2] = {(const float*)d_in[6],  (const float*)d_in[16]};
    const float* Wl_iu[2] = {(const float*)d_in[7],  (const float*)d_in[17]};
    const float* bl_iu[2] = {(const float*)d_in[8],  (const float*)d_in[18]};
    const float* Wr_iu[2] = {(const float*)d_in[9],  (const float*)d_in[19]};
    const float* g_user[2] = {(const float*)d_in[10], (const float*)d_in[20]};
    const float* b_user[2] = {(const float*)d_in[11], (const float*)d_in[21]};
    const float* g_item[2] = {(const float*)d_in[12], (const float*)d_in[22]};
    const float* b_item[2] = {(const float*)d_in[13], (const float*)d_in[23]};

    auto align = [](size_t x) { return (x + 255) & ~(size_t)255; };
    char* w = (char*)d_ws;
    int* cur = (int*)w; w += align((size_t)2 * NBK * 4);
    int2* bkt = (int2*)w; w += align((size_t)2 * NBK * BCAP * 8);
    int* csr = (int*)w; w += align((size_t)2 * NBK * BCAP * 4);
    int* rp_ui = (int*)w; w += align((size_t)NN * 4);
    int* re_ui = (int*)w; w += align((size_t)NN * 4);
    int* rp_iu = (int*)w; w += align((size_t)NN * 4);
    int* re_iu = (int*)w; w += align((size_t)NN * 4);
    unsigned short* Wb = (unsigned short*)w; w += align((size_t)8 * 16384 * 2);
    unsigned short* xb_user = (unsigned short*)w; w += align((size_t)NN * CC * 2);
    unsigned short* xb_item = (unsigned short*)w; w += align((size_t)NN * CC * 2);
    unsigned short* w_user = (unsigned short*)w; w += align((size_t)NN * CC * 2);
    unsigned short* w_item = (unsigned short*)w; w += align((size_t)NN * CC * 2);
    unsigned short* mean_item = (unsigned short*)w; w += align((size_t)NN * CC * 2);
    unsigned short* mean_user = (unsigned short*)w; w += align((size_t)NN * CC * 2);

    float* out_user = (float*)d_out;
    float* out_item = (float*)d_out + (size_t)NN * CC;

    // ---- cursors -> 0, then bucketing + all bf16 conversions in one launch ----
    hipMemsetAsync(cur, 0, (size_t)(2 * NBK) * sizeof(int), stream);
    k_preall<<<2 * BBLK + 2 * CVB2 + 64, 256, 0, stream>>>(
        ei_ui, ei_iu, cur, bkt,
        x_user, x_item, xb_user, xb_item,
        Wl_ui[0], Wr_ui[0], Wl_iu[0], Wr_iu[0],
        Wl_ui[1], Wr_ui[1], Wl_iu[1], Wr_iu[1], Wb);
    k_csr<<<2 * NBK, 256, 0, stream>>>(cur, bkt, rp_ui, re_ui, rp_iu, re_iu, csr);

    // ---- layer 0 (all bf16) ----
    k_agg2<<<2 * AB, 256, 0, stream>>>(xb_user, rp_ui, re_ui, mean_item,
                                       xb_item, rp_iu, re_iu, mean_user, csr);
    k_gemm2<false><<<2 * GBD, 1024, 0, stream>>>(
        mean_item, xb_item, Wb + 0 * 16384, Wb + 1 * 16384,
        bl_ui[0], g_item[0], b_item[0], w_item,
        mean_user, xb_user, Wb + 2 * 16384, Wb + 3 * 16384,
        bl_iu[0], g_user[0], b_user[0], w_user);

    // ---- layer 1 (all bf16) ----
    k_agg2<<<2 * AB, 256, 0, stream>>>(w_user, rp_ui, re_ui, mean_item,
                                       w_item, rp_iu, re_iu, mean_user, csr);
    k_gemm2<true><<<2 * GBD, 1024, 0, stream>>>(
        mean_item, w_item, Wb + 4 * 16384, Wb + 5 * 16384,
        bl_ui[1], g_item[1], b_item[1], out_item,
        mean_user, w_user, Wb + 6 * 16384, Wb + 7 * 16384,
        bl_iu[1], g_user[1], b_user[1], out_user);
}

// Round 19
// 271.897 us; speedup vs baseline: 1.1112x; 1.0170x over previous
//
#include <hip/hip_runtime.h>

#define NN 100000
#define NE 600000
#define CC 128
#define CVB2 3125            // NN*CC / 4096 (conversion blocks per array)
#define AB 6250              // NN / 16 (nodes per agg block = 16)
#define GBD 782              // ceil(NN / 128)
#define NBK 49               // coarse buckets per graph (dst >> 11)
#define BCAP 16384           // slots per bucket (expected ~12245, 34 sigma margin)
#define EPB 2048             // edges per block in bucket pass (8/thread)
#define BBLK 293             // ceil(NE / EPB)

typedef __attribute__((ext_vector_type(8))) short short8v;
typedef __attribute__((ext_vector_type(8))) unsigned short ushort8v;
typedef __attribute__((ext_vector_type(4))) unsigned short ushort4v;
typedef __attribute__((ext_vector_type(4))) float float4v;

__device__ __forceinline__ unsigned short f2bf(float f) {
    union { float f; unsigned u; } c; c.f = f;
    unsigned r = c.u + 0x7FFFu + ((c.u >> 16) & 1u);   // RNE
    return (unsigned short)(r >> 16);
}
__device__ __forceinline__ float bf2f(unsigned short u) {
    union { unsigned u; float f; } c; c.u = (unsigned)u << 16;
    return c.f;
}
__device__ __forceinline__ void addu8(float4& lo, float4& hi, ushort8v u) {
    lo.x += bf2f(u[0]); lo.y += bf2f(u[1]); lo.z += bf2f(u[2]); lo.w += bf2f(u[3]);
    hi.x += bf2f(u[4]); hi.y += bf2f(u[5]); hi.z += bf2f(u[6]); hi.w += bf2f(u[7]);
}
__device__ __forceinline__ ushort8v cvt8(const float* p) {
    float4 a = *reinterpret_cast<const float4*>(p);
    float4 b = *reinterpret_cast<const float4*>(p + 4);
    ushort8v h;
    h[0] = f2bf(a.x); h[1] = f2bf(a.y); h[2] = f2bf(a.z); h[3] = f2bf(a.w);
    h[4] = f2bf(b.x); h[5] = f2bf(b.y); h[6] = f2bf(b.z); h[7] = f2bf(b.w);
    return h;
}

// ---- k_preall: edge bucketing (both graphs) + x->bf16 + W->bf16, one launch.
// cur[] zeroed by hipMemsetAsync before this launch.
// Bucket phase: all 16 edge loads (8 dst + 8 src) batched into registers at
// entry (16x MLP); dsts reused for both histogram and scatter passes.

__global__ __launch_bounds__(256)
void k_preall(const int* __restrict__ ei0, const int* __restrict__ ei1,
              int* __restrict__ cur, int2* __restrict__ bkt,
              const float* __restrict__ xu, const float* __restrict__ xi,
              unsigned short* __restrict__ xbu, unsigned short* __restrict__ xbi,
              const float* w0, const float* w1, const float* w2, const float* w3,
              const float* w4, const float* w5, const float* w6, const float* w7,
              unsigned short* __restrict__ Wb) {
    __shared__ int hist[NBK];
    __shared__ int basew[NBK];
    int bid = blockIdx.x, t = threadIdx.x;
    if (bid < 2 * BBLK) {
        int g = (bid >= BBLK) ? 1 : 0;
        const int* ei = g ? ei1 : ei0;
        int local = g ? bid - BBLK : bid;
        int e0 = local * EPB;
        int cnt = NE - e0; if (cnt > EPB) cnt = EPB;
        if (cnt <= 0) return;
        // batch all edge loads up front (independent; 16 in flight)
        int dsts[8], srcs[8];
#pragma unroll
        for (int u = 0; u < 8; ++u) {
            int i = t + u * 256;
            dsts[u] = (i < cnt) ? ei[NE + e0 + i] : -1;
            srcs[u] = (i < cnt) ? ei[e0 + i] : 0;
        }
        if (t < NBK) hist[t] = 0;
        __syncthreads();
#pragma unroll
        for (int u = 0; u < 8; ++u)
            if (dsts[u] >= 0) atomicAdd(&hist[dsts[u] >> 11], 1);
        __syncthreads();
        if (t < NBK) {
            basew[t] = atomicAdd(&cur[g * NBK + t], hist[t]);
            hist[t] = 0;
        }
        __syncthreads();
        int2* bg = bkt + (size_t)g * NBK * BCAP;
#pragma unroll
        for (int u = 0; u < 8; ++u) {
            if (dsts[u] >= 0) {
                int b = dsts[u] >> 11;
                int r = atomicAdd(&hist[b], 1);
                int pos = basew[b] + r;
                if (pos < BCAP)
                    bg[(size_t)b * BCAP + pos] = make_int2(srcs[u], dsts[u]);
            }
        }
        return;
    }
    bid -= 2 * BBLK;
    if (bid < 2 * CVB2) {
        const float* src = (bid < CVB2) ? xu : xi;
        unsigned short* dst = (bid < CVB2) ? xbu : xbi;
        int local = (bid < CVB2) ? bid : bid - CVB2;
        size_t idx = (size_t)local * 4096 + t * 8;
        ushort8v a = cvt8(src + idx);
        ushort8v b = cvt8(src + idx + 2048);
        *reinterpret_cast<ushort8v*>(dst + idx) = a;
        *reinterpret_cast<ushort8v*>(dst + idx + 2048) = b;
        return;
    }
    bid -= 2 * CVB2;
    int m = bid >> 3;
    const float* src = w0;
    if (m == 1) src = w1; else if (m == 2) src = w2; else if (m == 3) src = w3;
    else if (m == 4) src = w4; else if (m == 5) src = w5;
    else if (m == 6) src = w6; else if (m == 7) src = w7;
    size_t idx = (size_t)(bid & 7) * 2048 + t * 8;
    *reinterpret_cast<ushort8v*>(Wb + (size_t)m * 16384 + idx) = cvt8(src + idx);
}

// ---- k_csr: per-bucket counting sort -> padded CSR + rp/re ----

__global__ __launch_bounds__(256)
void k_csr(const int* __restrict__ cnts, const int2* __restrict__ bkt,
           int* __restrict__ rp0, int* __restrict__ re0,
           int* __restrict__ rp1, int* __restrict__ re1,
           int* __restrict__ csr) {
    __shared__ int deg[2048];
    __shared__ int curp[2048];
    __shared__ int s[256];
    int bid = blockIdx.x;
    int g = (bid >= NBK) ? 1 : 0;
    int bb = g ? bid - NBK : bid;
    int t = threadIdx.x;
    const int2* eb = bkt + (size_t)(g * NBK + bb) * BCAP;
    int cnt = cnts[g * NBK + bb];
    if (cnt > BCAP) cnt = BCAP;
    int dbase = bb * 2048;
    int cb = (g * NBK + bb) * BCAP;
    int* rp = g ? rp1 : rp0;
    int* re = g ? re1 : re0;
    for (int i = t; i < 2048; i += 256) deg[i] = 0;
    __syncthreads();
    for (int i = t; i < cnt; i += 256) {
        int2 e = eb[i];
        atomicAdd(&deg[e.y - dbase], 1);
    }
    __syncthreads();
    int loc[8]; int v = 0; int b8 = t * 8;
#pragma unroll
    for (int u = 0; u < 8; ++u) { loc[u] = deg[b8 + u]; v += loc[u]; }
    s[t] = v; __syncthreads();
    for (int off = 1; off < 256; off <<= 1) {
        int x = (t >= off) ? s[t - off] : 0;
        __syncthreads();
        s[t] += x;
        __syncthreads();
    }
    int run = s[t] - v;
#pragma unroll
    for (int u = 0; u < 8; ++u) {
        int d = b8 + u;
        int gd = dbase + d;
        int start = cb + run;
        curp[d] = start;
        if (gd < NN) { rp[gd] = start; re[gd] = start + loc[u]; }
        run += loc[u];
    }
    __syncthreads();
    for (int i = t; i < cnt; i += 256) {
        int2 e = eb[i];
        int p = atomicAdd(&curp[e.y - dbase], 1);
        csr[p] = e.x;
    }
}

// ------------- aggregation (both directions in one launch), bf16 -------------

__global__ __launch_bounds__(256)
void k_agg2(const unsigned short* __restrict__ s0, const int* __restrict__ rp0,
            const int* __restrict__ re0, unsigned short* __restrict__ m0,
            const unsigned short* __restrict__ s1, const int* __restrict__ rp1,
            const int* __restrict__ re1, unsigned short* __restrict__ m1,
            const int* __restrict__ csr) {
    int bid = blockIdx.x;
    const unsigned short* src; const int* rp; const int* re; unsigned short* mean;
    if (bid < AB) { src = s0; rp = rp0; re = re0; mean = m0; }
    else { bid -= AB; src = s1; rp = rp1; re = re1; mean = m1; }
    int t = threadIdx.x;
    int node = bid * 16 + (t >> 4);
    int j0 = (t & 15) * 8;
    int b = rp[node], e = re[node];
    float4 z = make_float4(0.f, 0.f, 0.f, 0.f);
    float4 l0 = z, h0 = z, l1 = z, h1 = z, l2 = z, h2 = z, l3 = z, h3 = z;
    int i = b;
    for (; i + 4 <= e; i += 4) {
        int a = csr[i], bb = csr[i + 1], c = csr[i + 2], d = csr[i + 3];
        ushort8v u0 = *reinterpret_cast<const ushort8v*>(src + (size_t)a * CC + j0);
        ushort8v u1 = *reinterpret_cast<const ushort8v*>(src + (size_t)bb * CC + j0);
        ushort8v u2 = *reinterpret_cast<const ushort8v*>(src + (size_t)c * CC + j0);
        ushort8v u3 = *reinterpret_cast<const ushort8v*>(src + (size_t)d * CC + j0);
        addu8(l0, h0, u0); addu8(l1, h1, u1); addu8(l2, h2, u2); addu8(l3, h3, u3);
    }
    for (; i + 2 <= e; i += 2) {
        int a = csr[i], bb = csr[i + 1];
        ushort8v u0 = *reinterpret_cast<const ushort8v*>(src + (size_t)a * CC + j0);
        ushort8v u1 = *reinterpret_cast<const ushort8v*>(src + (size_t)bb * CC + j0);
        addu8(l0, h0, u0); addu8(l1, h1, u1);
    }
    if (i < e) {
        int a = csr[i];
        addu8(l0, h0, *reinterpret_cast<const ushort8v*>(src + (size_t)a * CC + j0));
    }
    int dg = e - b;
    float inv = 1.f / (float)(dg > 1 ? dg : 1);
    float m_[8];
    m_[0] = ((l0.x + l1.x) + (l2.x + l3.x)) * inv;
    m_[1] = ((l0.y + l1.y) + (l2.y + l3.y)) * inv;
    m_[2] = ((l0.z + l1.z) + (l2.z + l3.z)) * inv;
    m_[3] = ((l0.w + l1.w) + (l2.w + l3.w)) * inv;
    m_[4] = ((h0.x + h1.x) + (h2.x + h3.x)) * inv;
    m_[5] = ((h0.y + h1.y) + (h2.y + h3.y)) * inv;
    m_[6] = ((h0.z + h1.z) + (h2.z + h3.z)) * inv;
    m_[7] = ((h0.w + h1.w) + (h2.w + h3.w)) * inv;
    ushort8v h;
#pragma unroll
    for (int k = 0; k < 8; ++k) h[k] = f2bf(m_[k]);
    *reinterpret_cast<ushort8v*>(mean + (size_t)node * CC + j0) = h;
}

// ------- MFMA fused GEMM+LN+ReLU, both directions in one launch -------
// Round-12 verified structure: 1024 thr = 16 waves (2 mg x 8 ng), tile 128x128,
// K=256, all-bf16, hoisted Wl fragments, LN epilogue under t < 512.

template<bool OUTF32>
__global__ __launch_bounds__(1024, 4)
void k_gemm2(const unsigned short* __restrict__ mean0, const unsigned short* __restrict__ x0,
             const unsigned short* __restrict__ wl0, const unsigned short* __restrict__ wr0,
             const float* __restrict__ bl0, const float* __restrict__ g0,
             const float* __restrict__ bb0, void* __restrict__ out0,
             const unsigned short* __restrict__ mean1, const unsigned short* __restrict__ x1,
             const unsigned short* __restrict__ wl1, const unsigned short* __restrict__ wr1,
             const float* __restrict__ bl1, const float* __restrict__ g1,
             const float* __restrict__ bb1, void* __restrict__ out1) {
    __shared__ char sA[128 * 512];              // 64 KB bf16 A tile, then fp32 LN buf
    __shared__ float sbl[128], sg[128], sb[128];

    int bid = blockIdx.x;
    const unsigned short *mean, *xs, *wl, *wr;
    const float *bl, *g, *bb;
    void* out;
    if (bid < GBD) { mean = mean0; xs = x0; wl = wl0; wr = wr0; bl = bl0; g = g0; bb = bb0; out = out0; }
    else { bid -= GBD; mean = mean1; xs = x1; wl = wl1; wr = wr1; bl = bl1; g = g1; bb = bb1; out = out1; }

    int t = threadIdx.x;
    int base = bid * 128;
    if (t < 128) { sbl[t] = bl[t]; sg[t] = g[t]; sb[t] = bb[t]; }

    int wid = t >> 6, l = t & 63;
    int mg = wid >> 3, ng = wid & 7;        // 2 mg x 8 ng
    int l15 = l & 15, l4 = l >> 4;

    // ---- hoisted: khalf=0 (Wl) B-fragments, issued before staging ----
    short8v bf0[4];
    {
        int j = ng * 16 + l15;
        const unsigned short* wrow = wl + (size_t)j * CC + l4 * 8;
#pragma unroll
        for (int kk4 = 0; kk4 < 4; ++kk4)
            bf0[kk4] = *reinterpret_cast<const short8v*>(wrow + kk4 * 32);
    }

    // ---- stage A tile (both halves bf16): 8 threads/row ----
    {
        int r = t >> 3, q = t & 7;
        int swz = (r & 7) << 4;
        int node = base + r;
        bool valid = node < NN;
        const unsigned short* mrow = mean + (size_t)node * CC;
        const unsigned short* xrow = xs + (size_t)node * CC;
        ushort8v zz = (ushort8v){0, 0, 0, 0, 0, 0, 0, 0};
#pragma unroll
        for (int j = 0; j < 2; ++j) {
            int col = (j * 8 + q) * 8;
            ushort8v hm = valid ? *reinterpret_cast<const ushort8v*>(mrow + col) : zz;
            *reinterpret_cast<ushort8v*>(sA + ((r * 512 + col * 2) ^ swz)) = hm;
            ushort8v hx = valid ? *reinterpret_cast<const ushort8v*>(xrow + col) : zz;
            *reinterpret_cast<ushort8v*>(sA + ((r * 512 + 256 + col * 2) ^ swz)) = hx;
        }
    }
    __syncthreads();

    float4v acc[4];
#pragma unroll
    for (int mt = 0; mt < 4; ++mt)
        acc[mt] = (float4v){0.f, 0.f, 0.f, 0.f};

    // ---- khalf = 0 (mean half, Wl) ----
#pragma unroll
    for (int kk4 = 0; kk4 < 4; ++kk4) {
        short8v af[4];
#pragma unroll
        for (int mt = 0; mt < 4; ++mt) {
            int row = mg * 64 + mt * 16 + l15;
            int byte = (row * 512 + l4 * 16 + kk4 * 64) ^ ((row & 7) << 4);
            af[mt] = *reinterpret_cast<short8v*>(sA + byte);
        }
#pragma unroll
        for (int mt = 0; mt < 4; ++mt)
            acc[mt] = __builtin_amdgcn_mfma_f32_16x16x32_bf16(
                af[mt], bf0[kk4], acc[mt], 0, 0, 0);
    }

    // ---- khalf = 1 (x half, Wr) ----
    {
        short8v bf1[4];
        {
            int j = ng * 16 + l15;
            const unsigned short* wrow = wr + (size_t)j * CC + l4 * 8;
#pragma unroll
            for (int kk4 = 0; kk4 < 4; ++kk4)
                bf1[kk4] = *reinterpret_cast<const short8v*>(wrow + kk4 * 32);
        }
#pragma unroll
        for (int kk4 = 0; kk4 < 4; ++kk4) {
            short8v af[4];
#pragma unroll
            for (int mt = 0; mt < 4; ++mt) {
                int row = mg * 64 + mt * 16 + l15;
                int byte = (row * 512 + l4 * 16 + (4 + kk4) * 64) ^ ((row & 7) << 4);
                af[mt] = *reinterpret_cast<short8v*>(sA + byte);
            }
#pragma unroll
            for (int mt = 0; mt < 4; ++mt)
                acc[mt] = __builtin_amdgcn_mfma_f32_16x16x32_bf16(
                    af[mt], bf1[kk4], acc[mt], 0, 0, 0);
        }
    }
    __syncthreads();   // A tile free; reuse as fp32 LN buffer

    // ---- scatter biased acc -> LDS fp32 (same swizzle) ----
#pragma unroll
    for (int mt = 0; mt < 4; ++mt)
#pragma unroll
        for (int r4 = 0; r4 < 4; ++r4) {
            int nrow = mg * 64 + mt * 16 + l4 * 4 + r4;
            int col = ng * 16 + l15;
            float v = acc[mt][r4] + sbl[col];
            int byte = (nrow * 512 + col * 4) ^ ((nrow & 7) << 4);
            *reinterpret_cast<float*>(sA + byte) = v;
        }
    __syncthreads();

    // ---- transposed LN + ReLU + store (verbatim round-7 path, t < 512) ----
    if (t < 512) {
        int nn_ = t >> 2, qq = t & 3;
        int gnode = base + nn_;
        float s1 = 0.f, s2 = 0.f;
        float4 vv[8];
#pragma unroll
        for (int u = 0; u < 8; ++u) {
            int c = qq * 4 + u * 16;
            int byte = (nn_ * 512 + c * 4) ^ ((nn_ & 7) << 4);
            float4 vx = *reinterpret_cast<float4*>(sA + byte);
            vv[u] = vx;
            s1 += vx.x + vx.y + vx.z + vx.w;
            s2 += vx.x * vx.x + vx.y * vx.y + vx.z * vx.z + vx.w * vx.w;
        }
        s1 += __shfl_xor(s1, 1); s1 += __shfl_xor(s1, 2);
        s2 += __shfl_xor(s2, 1); s2 += __shfl_xor(s2, 2);
        float mu = s1 * (1.f / 128.f);
        float var = s2 * (1.f / 128.f) - mu * mu;
        float rstd = rsqrtf(var + 1e-5f);
        if (gnode < NN) {
#pragma unroll
            for (int u = 0; u < 8; ++u) {
                int c = qq * 4 + u * 16;
                float4 vx = vv[u];
                float4 o;
                o.x = fmaxf(0.f, (vx.x - mu) * rstd * sg[c + 0] + sb[c + 0]);
                o.y = fmaxf(0.f, (vx.y - mu) * rstd * sg[c + 1] + sb[c + 1]);
                o.z = fmaxf(0.f, (vx.z - mu) * rstd * sg[c + 2] + sb[c + 2]);
                o.w = fmaxf(0.f, (vx.w - mu) * rstd * sg[c + 3] + sb[c + 3]);
                if (OUTF32) {
                    float* op = (float*)out + (size_t)gnode * CC;
                    *reinterpret_cast<float4*>(op + c) = o;
                } else {
                    unsigned short* op = (unsigned short*)out + (size_t)gnode * CC;
                    ushort4v h; h.x = f2bf(o.x); h.y = f2bf(o.y); h.z = f2bf(o.z); h.w = f2bf(o.w);
                    *reinterpret_cast<ushort4v*>(op + c) = h;
                }
            }
        }
    }
}

// ---------------- launch ----------------

extern "C" void kernel_launch(void* const* d_in, const int* in_sizes, int n_in,
                              void* d_out, int out_size, void* d_ws, size_t ws_size,
                              hipStream_t stream) {
    const float* x_user = (const float*)d_in[0];
    const float* x_item = (const float*)d_in[1];
    const int* ei_ui = (const int*)d_in[2];
    const int* ei_iu = (const int*)d_in[3];

    const float* Wl_ui[2] = {(const float*)d_in[4],  (const float*)d_in[14]};
    const float* bl_ui[2] = {(const float*)d_in[5],  (const float*)d_in[15]};
    const float* Wr_ui[2] = {(const float*)d_in[6],  (const float*)d_in[16]};
    const float* Wl_iu[2] = {(const float*)d_in[7],  (const float*)d_in[17]};
    const float* bl_iu[2] = {(const float*)d_in[8],  (const float*)d_in[18]};
    const float* Wr_iu[2] = {(const float*)d_in[9],  (const float*)d_in[19]};
    const float* g_user[2] = {(const float*)d_in[10], (const float*)d_in[20]};
    const float* b_user[2] = {(const float*)d_in[11], (const float*)d_in[21]};
    const float* g_item[2] = {(const float*)d_in[12], (const float*)d_in[22]};
    const float* b_item[2] = {(const float*)d_in[13], (const float*)d_in[23]};

    auto align = [](size_t x) { return (x + 255) & ~(size_t)255; };
    char* w = (char*)d_ws;
    int* cur = (int*)w; w += align((size_t)2 * NBK * 4);
    int2* bkt = (int2*)w; w += align((size_t)2 * NBK * BCAP * 8);
    int* csr = (int*)w; w += align((size_t)2 * NBK * BCAP * 4);
    int* rp_ui = (int*)w; w += align((size_t)NN * 4);
    int* re_ui = (int*)w; w += align((size_t)NN * 4);
    int* rp_iu = (int*)w; w += align((size_t)NN * 4);
    int* re_iu = (int*)w; w += align((size_t)NN * 4);
    unsigned short* Wb = (unsigned short*)w; w += align((size_t)8 * 16384 * 2);
    unsigned short* xb_user = (unsigned short*)w; w += align((size_t)NN * CC * 2);
    unsigned short* xb_item = (unsigned short*)w; w += align((size_t)NN * CC * 2);
    unsigned short* w_user = (unsigned short*)w; w += align((size_t)NN * CC * 2);
    unsigned short* w_item = (unsigned short*)w; w += align((size_t)NN * CC * 2);
    unsigned short* mean_item = (unsigned short*)w; w += align((size_t)NN * CC * 2);
    unsigned short* mean_user = (unsigned short*)w; w += align((size_t)NN * CC * 2);

    float* out_user = (float*)d_out;
    float* out_item = (float*)d_out + (size_t)NN * CC;

    // ---- cursors -> 0, then bucketing + all bf16 conversions in one launch ----
    hipMemsetAsync(cur, 0, (size_t)(2 * NBK) * sizeof(int), stream);
    k_preall<<<2 * BBLK + 2 * CVB2 + 64, 256, 0, stream>>>(
        ei_ui, ei_iu, cur, bkt,
        x_user, x_item, xb_user, xb_item,
        Wl_ui[0], Wr_ui[0], Wl_iu[0], Wr_iu[0],
        Wl_ui[1], Wr_ui[1], Wl_iu[1], Wr_iu[1], Wb);
    k_csr<<<2 * NBK, 256, 0, stream>>>(cur, bkt, rp_ui, re_ui, rp_iu, re_iu, csr);

    // ---- layer 0 (all bf16) ----
    k_agg2<<<2 * AB, 256, 0, stream>>>(xb_user, rp_ui, re_ui, mean_item,
                                       xb_item, rp_iu, re_iu, mean_user, csr);
    k_gemm2<false><<<2 * GBD, 1024, 0, stream>>>(
        mean_item, xb_item, Wb + 0 * 16384, Wb + 1 * 16384,
        bl_ui[0], g_item[0], b_item[0], w_item,
        mean_user, xb_user, Wb + 2 * 16384, Wb + 3 * 16384,
        bl_iu[0], g_user[0], b_user[0], w_user);

    // ---- layer 1 (all bf16) ----
    k_agg2<<<2 * AB, 256, 0, stream>>>(w_user, rp_ui, re_ui, mean_item,
                                       w_item, rp_iu, re_iu, mean_user, csr);
    k_gemm2<true><<<2 * GBD, 1024, 0, stream>>>(
        mean_item, w_item, Wb + 4 * 16384, Wb + 5 * 16384,
        bl_ui[1], g_item[1], b_item[1], out_item,
        mean_user, w_user, Wb + 6 * 16384, Wb + 7 * 16384,
        bl_iu[1], g_user[1], b_user[1], out_user);
}